// Round 10
// baseline (132.553 us; speedup 1.0000x reference)
//
#include <hip/hip_runtime.h>

typedef unsigned short u16;
typedef _Float16 f16;

#define CIN   64
#define HH    128
#define WW    128
#define NPIX  16384   /* HH*WW */
#define HID   256
#define MTOT  512     /* coef(256) + freq(256) stacked */
#define KTOT  576     /* 64 ch * 9 taps */
#define NB    4
#define WELEM 294912  /* MTOT*KTOT */
#define XROW  130     /* padded input grid row */
#define XROWS 16900   /* 130*130 rows per batch */

/* index-path constants: must bit-match the f32 trace of the reference */
#define SHM  ((float)(-0.0078125 + 1e-6))
#define SHP  ((float)( 0.0078125 + 1e-6))
#define CLO  ((float)(-1.0 + 1e-6))
#define CHI  ((float)( 1.0 - 1e-6))
#define PIF  3.14159265358979323846f

#define QSCL  1024.0f          /* int16 fixed-point scale for YT */
#define QISCL (1.0f / 1024.0f)

using f32x4 = __attribute__((ext_vector_type(4))) float;
using f16x8 = __attribute__((ext_vector_type(8))) _Float16;

/* ---- async global->LDS DMA, 16B per lane (dest = wave base + lane*16) ---- */
typedef __attribute__((address_space(1))) const void gas_void;
typedef __attribute__((address_space(3))) void las_void;
__device__ __forceinline__ void gload16(const void* g, void* l) {
  __builtin_amdgcn_global_load_lds((gas_void*)g, (las_void*)l, 16, 0, 0);
}

/* ---- int16 fixed-point YT helpers ---- */
__device__ __forceinline__ float ldq(const short* p) { return (float)(*p) * QISCL; }
__device__ __forceinline__ void ldqpair(const short* p, float& a, float& b) {
  int u = *(const int*)p;
  a = (float)((short)(u & 0xFFFF)) * QISCL;
  b = (float)((short)(u >> 16)) * QISCL;
}
__device__ __forceinline__ unsigned packq(float a, float b) {
  float fa = fminf(fmaxf(a * QSCL, -32767.f), 32767.f);
  float fb = fminf(fmaxf(b * QSCL, -32767.f), 32767.f);
  int ia = (int)rintf(fa), ib = (int)rintf(fb);
  return ((unsigned)(unsigned short)(short)ia) | (((unsigned)(unsigned short)(short)ib) << 16);
}
__device__ __forceinline__ void storeq4(short* p, float a, float b, float c, float d) {
  uint2 v; v.x = packq(a, b); v.y = packq(c, d);
  *(uint2*)p = v;
}

/* =====================================================================
 * Kernel 1: repack conv weights -> fp16 for DIRECT global->register
 * fragment loads: 1KB coalesced chunk per (mt, wr, s, ks, mi); lane l
 * holds halfs [jl*8..+8) of A-row (mt*128 + wr*64 + mi*16 + (l&15)),
 * jl = ks*4 + (l>>4), tap s. No LDS for A => no swizzle.
 * id = ((((((mt*2+wr)*9+s)*2+ks)*4+mi)*64)+l)*8+e
 * ===================================================================== */
__global__ __launch_bounds__(256) void lte_prep_w(
    const float* __restrict__ cw, const float* __restrict__ fw,
    f16* __restrict__ Awp) {
  int id = blockIdx.x * 256 + threadIdx.x;
  if (id >= WELEM) return;
  int e  = id & 7;
  int l  = (id >> 3) & 63;
  int mi = (id >> 9) & 3;
  int r  = id >> 11;
  int ks = r & 1;
  int r2 = r >> 1;
  int s  = r2 % 9;
  int q  = r2 / 9;
  int wr = q & 1;
  int mt = q >> 1;
  int m  = mt * 128 + wr * 64 + mi * 16 + (l & 15);
  int ch = (ks * 4 + (l >> 4)) * 8 + e;
  const float* src = (m < HID) ? cw : fw;
  Awp[id] = (f16)src[(m & 255) * KTOT + ch * 9 + s];
}

/* =====================================================================
 * Kernel 1b: input NCHW f32 -> zero-guard-padded pixel-major fp16
 * xp[b][130][130][64], 16B chunks XOR-permuted by (padded_col & 7) so
 * tap-shifted LDS B reads are bank-conflict-free (validated R9: 0).
 * ===================================================================== */
__global__ __launch_bounds__(256) void lte_prep_x(
    const float* __restrict__ inp, f16* __restrict__ xp) {
  int id = blockIdx.x * 256 + threadIdx.x;   /* padded row id, NB*16900 */
  if (id >= NB * XROWS) return;
  int b  = id / XROWS;
  int rr = id - b * XROWS;
  int yy = rr / XROW;
  int pc = rr - yy * XROW;      /* padded col 0..129 */
  int x  = pc - 1;
  int y  = yy - 1;
  f16* op = xp + (size_t)id * 64;
  if ((unsigned)y < 128u && (unsigned)x < 128u) {
    const float* ip = inp + (size_t)b * CIN * NPIX + y * WW + x;
    const int p7 = pc & 7;
#pragma unroll
    for (int q = 0; q < 8; ++q) {
      f16x8 v;
#pragma unroll
      for (int k = 0; k < 8; ++k) v[k] = (f16)ip[(((q ^ p7) << 3) + k) * NPIX];
      *(f16x8*)(op + q * 8) = v;
    }
  } else {
    f16x8 z = {};
#pragma unroll
    for (int q = 0; q < 8; ++q) *(f16x8*)(op + q * 8) = z;
  }
}

/* =====================================================================
 * Kernel 2: implicit-im2col GEMM, 128x128 tile, 4 waves (2x2), 4x4 frags.
 * BARRIER-FREE K-LOOP: B (3 padded image rows, 52KB) is staged ONCE in
 * the prologue and is read-only after; A fragments are loaded DIRECTLY
 * global->VGPR (coalesced 1KB chunks, L1/L2-resident). 9 steps of pure
 * {global A loads | ds_read B | 32 MFMA} — per-wave scoreboarding only,
 * compiler free to pipeline across steps. 12 independent waves/CU.
 * Output pixel-major int16 YT[b][p][512] (+bias), scale 1024.
 * ===================================================================== */
__global__ __launch_bounds__(256, 3) void lte_conv_gemm(
    const f16* __restrict__ xp, const f16* __restrict__ Awp,
    const float* __restrict__ coef_b, const float* __restrict__ freq_b,
    short* __restrict__ YT) {
  __shared__ f16 Bs[3 * 136 * 64];    /* 52,224 B */

  const int t  = threadIdx.x;
  const int bx = blockIdx.x;     /* image row y; pixel tile = [bx*128,+128) */
  const int mt = blockIdx.y;     /* m tile (0..3) */
  const int bb = blockIdx.z;     /* batch */
  const int l  = t & 63;
  const int w  = t >> 6;
  const int wr = __builtin_amdgcn_readfirstlane(w >> 1);
  const int wc = __builtin_amdgcn_readfirstlane(w & 1);
  const int lm = l & 15;

  f32x4 acc[4][4] = {};

  const f16* xb = xp + (size_t)bb * XROWS * 64;
  /* wave's A stream: 9 steps x 8 chunks x 1KB, fully coalesced */
  const f16* Aw = Awp + (size_t)((mt * 2 + wr) * 9) * 4096;

  /* ---- prologue: stage B rows bx-1..bx+1 (padded idx bx..bx+2),
     51 x 1KB DMA calls (rr<3, cc<17: 8 px of 128B each) ---- */
  for (int c = w; c < 51; c += 4) {
    const int rr = c / 17, cc = c - rr * 17;
    gload16(xb + (size_t)((bx + rr) * XROW + cc * 8) * 64 + l * 8,
            Bs + (rr * 136 + cc * 8) * 64);
  }
  asm volatile("s_waitcnt vmcnt(0)" ::: "memory");
  __builtin_amdgcn_s_barrier();

  for (int s = 0; s < 9; ++s) {
    const int ky = s / 3, kx = s - 3 * (s / 3);
    const f16* As = Aw + s * 4096;
#pragma unroll
    for (int ks = 0; ks < 2; ++ks) {
      f16x8 af[4], bg[4];
#pragma unroll
      for (int mi = 0; mi < 4; ++mi)
        af[mi] = *(const f16x8*)(As + (ks * 4 + mi) * 512 + l * 8);
      const int jl = ks * 4 + (l >> 4);
#pragma unroll
      for (int ni = 0; ni < 4; ++ni) {
        const int xc = wc * 64 + ni * 16 + lm + kx;
        bg[ni] = *(const f16x8*)&Bs[(ky * 136 + xc) * 64 + ((jl ^ (xc & 7)) << 3)];
      }
#pragma unroll
      for (int mi = 0; mi < 4; ++mi)
#pragma unroll
        for (int ni = 0; ni < 4; ++ni)
          acc[mi][ni] = __builtin_amdgcn_mfma_f32_16x16x32_f16(af[mi], bg[ni], acc[mi][ni], 0, 0, 0);
    }
  }

  /* epilogue: +bias, quantize, store pixel-major YT[b][p][512] */
  const float* bias = (mt < 2) ? (coef_b + mt * 128) : (freq_b + (mt - 2) * 128);
  const int rj = (l >> 4) * 4;
#pragma unroll
  for (int mi = 0; mi < 4; ++mi) {
    const int bm = wr * 64 + mi * 16 + rj;
    const float b0 = bias[bm], b1 = bias[bm + 1], b2 = bias[bm + 2], b3 = bias[bm + 3];
#pragma unroll
    for (int ni = 0; ni < 4; ++ni) {
      const int p = bx * 128 + wc * 64 + ni * 16 + lm;
      size_t off = ((size_t)(bb * NPIX + p)) * 512 + mt * 128 + bm;
      f32x4 v = acc[mi][ni];
      storeq4(&YT[off], v[0] + b0, v[1] + b1, v[2] + b2, v[3] + b3);
    }
  }
}

/* =====================================================================
 * Kernel 3: 4-corner nearest sample + sin/cos modulation (int16 YT).
 * Validated bit-exact index path — unchanged.
 * ===================================================================== */
__global__ __launch_bounds__(128) void lte_sample(
    const short* __restrict__ YT, const float* __restrict__ coord,
    const float* __restrict__ cell, const float* __restrict__ phase_w,
    float* __restrict__ out) {
  __shared__ float lout[256 * 17];
  const int j     = threadIdx.x;          /* 0..127 */
  const int q0    = blockIdx.x * 16;      /* global over B*Q */
  const int b     = q0 >> 14;
  const int q0loc = q0 & (NPIX - 1);
  const float pw0 = phase_w[2 * j], pw1 = phase_w[2 * j + 1];
  const short* Yb = YT + ((size_t)b * NPIX) * 512;

  for (int qi = 0; qi < 16; ++qi) {
    const int qg = q0 + qi;
    const float c0  = coord[2 * qg], c1 = coord[2 * qg + 1];
    const float ce0 = cell[2 * qg],  ce1 = cell[2 * qg + 1];
    const float ph  = (ce0 * 128.0f) * pw0 + (ce1 * 128.0f) * pw1;
    float accC = 0.f, accS = 0.f, tot = 0.f, a3 = 0.f;
#pragma unroll
    for (int ci = 0; ci < 4; ++ci) {     /* (vx,vy): (-,-),(-,+),(+,-),(+,+) */
      const float s0 = (ci & 2) ? SHP : SHM;
      const float s1 = (ci & 1) ? SHP : SHM;
      float cx = fminf(fmaxf(c0 + s0, CLO), CHI);
      float cy = fminf(fmaxf(c1 + s1, CLO), CHI);
      float ty = ((cx + 1.0f) * 128.0f - 1.0f) * 0.5f;
      float tx = ((cy + 1.0f) * 128.0f - 1.0f) * 0.5f;
      float fy = fminf(fmaxf(rintf(ty), 0.f), 127.f);   /* round half-even */
      float fx = fminf(fmaxf(rintf(tx), 0.f), 127.f);
      int iy = (int)fy, ix = (int)fx;
      float qcy = -1.0f + (2.0f * fy + 1.0f) * (1.0f / 128.0f);
      float qcx = -1.0f + (2.0f * fx + 1.0f) * (1.0f / 128.0f);
      float rel0 = (c0 - qcy) * 128.0f;
      float rel1 = (c1 - qcx) * 128.0f;
      float ar = fabsf(rel0 * rel1);
      tot += ar + 1e-9f;
      if (ci == 3) a3 = ar;
      const short* bp = Yb + ((size_t)(iy * 128 + ix)) * 512;
      float coefA = ldq(bp + j);          /* coef channel j    */
      float coefB = ldq(bp + 128 + j);    /* coef channel j+128 */
      float f0, f1;
      ldqpair(bp + 256 + 2 * j, f0, f1);  /* freq pair (2j,2j+1) */
      float f = f0 * rel0 + f1 * rel1 + ph;
      float ang = PIF * f;
      accC += coefA * __cosf(ang);
      accS += coefB * __sinf(ang);
    }
    const float wgt = a3 / tot;
    lout[j * 17 + qi]         = accC * wgt;
    lout[(j + 128) * 17 + qi] = accS * wgt;
  }
  __syncthreads();
#pragma unroll
  for (int pass = 0; pass < 8; ++pass) {
    int c  = pass * 32 + (j >> 2);
    int qf = (j & 3) * 4;
    float4 v;
    v.x = lout[c * 17 + qf];     v.y = lout[c * 17 + qf + 1];
    v.z = lout[c * 17 + qf + 2]; v.w = lout[c * 17 + qf + 3];
    *(float4*)(out + (((size_t)(b * 256 + c)) << 14) + q0loc + qf) = v;
  }
}

extern "C" void kernel_launch(void* const* d_in, const int* in_sizes, int n_in,
                              void* d_out, int out_size, void* d_ws, size_t ws_size,
                              hipStream_t stream) {
  const float* inp     = (const float*)d_in[0];
  const float* coord   = (const float*)d_in[1];
  const float* cell    = (const float*)d_in[2];
  const float* coef_w  = (const float*)d_in[3];
  const float* coef_b  = (const float*)d_in[4];
  const float* freq_w  = (const float*)d_in[5];
  const float* freq_b  = (const float*)d_in[6];
  const float* phase_w = (const float*)d_in[7];
  float* out = (float*)d_out;

  /* ws: Awp fp16 (0.59MB) | xp_pad fp16 (8.65MB + slack) | YT int16 (67MB) */
  f16* Awp = (f16*)d_ws;
  f16* xp  = (f16*)((char*)d_ws + (size_t)WELEM * 2);
  short* YT = (short*)((char*)d_ws + (size_t)WELEM * 2
                       + ((size_t)NB * XROWS + 8) * 64 * 2);

  lte_prep_w<<<dim3(1152), dim3(256), 0, stream>>>(coef_w, freq_w, Awp);
  lte_prep_x<<<dim3((NB * XROWS + 255) / 256), dim3(256), 0, stream>>>(inp, xp);
  lte_conv_gemm<<<dim3(128, 4, 4), dim3(256), 0, stream>>>(xp, Awp, coef_b, freq_b, YT);
  lte_sample<<<dim3(4096), dim3(128), 0, stream>>>(YT, coord, cell, phase_w, out);
}

// Round 11
// 129.902 us; speedup vs baseline: 1.0204x; 1.0204x over previous
//
#include <hip/hip_runtime.h>

typedef unsigned short u16;
typedef _Float16 f16;

#define CIN   64
#define HH    128
#define WW    128
#define NPIX  16384   /* HH*WW */
#define HID   256
#define MTOT  512     /* coef(256) + freq(256) stacked */
#define KTOT  576     /* 64 ch * 9 taps */
#define NB    4
#define WELEM 294912  /* MTOT*KTOT */
#define XROW  130     /* padded input grid row */
#define XROWS 16900   /* 130*130 rows per batch */

/* index-path constants: must bit-match the f32 trace of the reference */
#define SHM  ((float)(-0.0078125 + 1e-6))
#define SHP  ((float)( 0.0078125 + 1e-6))
#define CLO  ((float)(-1.0 + 1e-6))
#define CHI  ((float)( 1.0 - 1e-6))
#define PIF  3.14159265358979323846f

#define QSCL  1024.0f          /* int16 fixed-point scale for YT */
#define QISCL (1.0f / 1024.0f)

using f32x4 = __attribute__((ext_vector_type(4))) float;
using f16x8 = __attribute__((ext_vector_type(8))) _Float16;

/* ---- async global->LDS DMA, 16B per lane (dest = wave base + lane*16) ---- */
typedef __attribute__((address_space(1))) const void gas_void;
typedef __attribute__((address_space(3))) void las_void;
__device__ __forceinline__ void gload16(const void* g, void* l) {
  __builtin_amdgcn_global_load_lds((gas_void*)g, (las_void*)l, 16, 0, 0);
}

/* ---- int16 fixed-point YT helpers ---- */
__device__ __forceinline__ float ldq(const short* p) { return (float)(*p) * QISCL; }
__device__ __forceinline__ void ldqpair(const short* p, float& a, float& b) {
  int u = *(const int*)p;
  a = (float)((short)(u & 0xFFFF)) * QISCL;
  b = (float)((short)(u >> 16)) * QISCL;
}
__device__ __forceinline__ unsigned packq(float a, float b) {
  float fa = fminf(fmaxf(a * QSCL, -32767.f), 32767.f);
  float fb = fminf(fmaxf(b * QSCL, -32767.f), 32767.f);
  int ia = (int)rintf(fa), ib = (int)rintf(fb);
  return ((unsigned)(unsigned short)(short)ia) | (((unsigned)(unsigned short)(short)ib) << 16);
}
__device__ __forceinline__ void storeq4(short* p, float a, float b, float c, float d) {
  uint2 v; v.x = packq(a, b); v.y = packq(c, d);
  *(uint2*)p = v;
}

/* =====================================================================
 * Kernel 1: repack conv weights -> fp16 for DIRECT global->register
 * fragment loads: 1KB coalesced chunk per (mt, wr, s, ks, mi); lane l
 * holds halfs [jl*8..+8) of A-row (mt*128 + wr*64 + mi*16 + (l&15)),
 * jl = ks*4 + (l>>4), tap s. No LDS for A => no swizzle.
 * ===================================================================== */
__global__ __launch_bounds__(256) void lte_prep_w(
    const float* __restrict__ cw, const float* __restrict__ fw,
    f16* __restrict__ Awp) {
  int id = blockIdx.x * 256 + threadIdx.x;
  if (id >= WELEM) return;
  int e  = id & 7;
  int l  = (id >> 3) & 63;
  int mi = (id >> 9) & 3;
  int r  = id >> 11;
  int ks = r & 1;
  int r2 = r >> 1;
  int s  = r2 % 9;
  int q  = r2 / 9;
  int wr = q & 1;
  int mt = q >> 1;
  int m  = mt * 128 + wr * 64 + mi * 16 + (l & 15);
  int ch = (ks * 4 + (l >> 4)) * 8 + e;
  const float* src = (m < HID) ? cw : fw;
  Awp[id] = (f16)src[(m & 255) * KTOT + ch * 9 + s];
}

/* =====================================================================
 * Kernel 1b: input NCHW f32 -> zero-guard-padded pixel-major fp16
 * xp[b][130][130][64], 16B chunks XOR-permuted by (padded_col & 7) so
 * tap-shifted LDS B reads are bank-conflict-free (validated R10: 0).
 * ===================================================================== */
__global__ __launch_bounds__(256) void lte_prep_x(
    const float* __restrict__ inp, f16* __restrict__ xp) {
  int id = blockIdx.x * 256 + threadIdx.x;   /* padded row id, NB*16900 */
  if (id >= NB * XROWS) return;
  int b  = id / XROWS;
  int rr = id - b * XROWS;
  int yy = rr / XROW;
  int pc = rr - yy * XROW;      /* padded col 0..129 */
  int x  = pc - 1;
  int y  = yy - 1;
  f16* op = xp + (size_t)id * 64;
  if ((unsigned)y < 128u && (unsigned)x < 128u) {
    const float* ip = inp + (size_t)b * CIN * NPIX + y * WW + x;
    const int p7 = pc & 7;
#pragma unroll
    for (int q = 0; q < 8; ++q) {
      f16x8 v;
#pragma unroll
      for (int k = 0; k < 8; ++k) v[k] = (f16)ip[(((q ^ p7) << 3) + k) * NPIX];
      *(f16x8*)(op + q * 8) = v;
    }
  } else {
    f16x8 z = {};
#pragma unroll
    for (int q = 0; q < 8; ++q) *(f16x8*)(op + q * 8) = z;
  }
}

/* =====================================================================
 * Kernel 2: implicit-im2col GEMM, 128x128 tile, 4 waves (2x2), 4x4 frags.
 * Barrier-free K-loop (R10, validated) + NEW: half-step register
 * double-buffer for A — issue the next half-step's 4 global af loads
 * into the alternate named buffer BEFORE computing the current one
 * (load-to-use distance = 16 MFMA ~ 230 cyc wall, covers L2 latency).
 * B (3 padded rows, 52KB LDS) staged once in prologue, read-only after.
 * Output pixel-major int16 YT[b][p][512] (+bias), scale 1024.
 * ===================================================================== */
__global__ __launch_bounds__(256, 3) void lte_conv_gemm(
    const f16* __restrict__ xp, const f16* __restrict__ Awp,
    const float* __restrict__ coef_b, const float* __restrict__ freq_b,
    short* __restrict__ YT) {
  __shared__ f16 Bs[3 * 136 * 64];    /* 52,224 B */

  const int t  = threadIdx.x;
  const int bx = blockIdx.x;     /* image row y; pixel tile = [bx*128,+128) */
  const int mt = blockIdx.y;     /* m tile (0..3) */
  const int bb = blockIdx.z;     /* batch */
  const int l  = t & 63;
  const int w  = t >> 6;
  const int wr = __builtin_amdgcn_readfirstlane(w >> 1);
  const int wc = __builtin_amdgcn_readfirstlane(w & 1);
  const int lm = l & 15;

  f32x4 acc[4][4] = {};

  const f16* xb = xp + (size_t)bb * XROWS * 64;
  /* wave's A stream: 18 half-steps x 4 chunks x 1KB, fully coalesced */
  const f16* Aw = Awp + (size_t)((mt * 2 + wr) * 9) * 4096 + l * 8;

  /* ---- prologue: stage B rows bx-1..bx+1 (padded idx bx..bx+2),
     51 x 1KB DMA calls; then issue half-step 0's A loads ---- */
  for (int c = w; c < 51; c += 4) {
    const int rr = c / 17, cc = c - rr * 17;
    gload16(xb + (size_t)((bx + rr) * XROW + cc * 8) * 64 + l * 8,
            Bs + (rr * 136 + cc * 8) * 64);
  }

  f16x8 afb[2][4];                     /* named dbuf; h&1 static after unroll */
#define LOAD_AF(buf_, h_)                                                    \
  {                                                                          \
    const f16* ap_ = Aw + ((h_) >> 1) * 4096 + ((h_) & 1) * 2048;            \
    afb[buf_][0] = *(const f16x8*)(ap_);                                     \
    afb[buf_][1] = *(const f16x8*)(ap_ + 512);                               \
    afb[buf_][2] = *(const f16x8*)(ap_ + 1024);                              \
    afb[buf_][3] = *(const f16x8*)(ap_ + 1536);                              \
  }

  LOAD_AF(0, 0)
  asm volatile("s_waitcnt vmcnt(0)" ::: "memory");
  __builtin_amdgcn_s_barrier();

#pragma unroll
  for (int h = 0; h < 18; ++h) {
    const int s  = h >> 1;
    const int ks = h & 1;
    if (h < 17) LOAD_AF((h + 1) & 1, h + 1)          /* issue-early */
    const int ky = s / 3, kx = s - 3 * (s / 3);
    const int jl = ks * 4 + (l >> 4);
    f16x8 bg[4];
#pragma unroll
    for (int ni = 0; ni < 4; ++ni) {
      const int xc = wc * 64 + ni * 16 + lm + kx;
      bg[ni] = *(const f16x8*)&Bs[(ky * 136 + xc) * 64 + ((jl ^ (xc & 7)) << 3)];
    }
#pragma unroll
    for (int mi = 0; mi < 4; ++mi)
#pragma unroll
      for (int ni = 0; ni < 4; ++ni)
        acc[mi][ni] = __builtin_amdgcn_mfma_f32_16x16x32_f16(afb[h & 1][mi], bg[ni], acc[mi][ni], 0, 0, 0);
  }

  /* epilogue: +bias, quantize, store pixel-major YT[b][p][512] */
  const float* bias = (mt < 2) ? (coef_b + mt * 128) : (freq_b + (mt - 2) * 128);
  const int rj = (l >> 4) * 4;
#pragma unroll
  for (int mi = 0; mi < 4; ++mi) {
    const int bm = wr * 64 + mi * 16 + rj;
    const float b0 = bias[bm], b1 = bias[bm + 1], b2 = bias[bm + 2], b3 = bias[bm + 3];
#pragma unroll
    for (int ni = 0; ni < 4; ++ni) {
      const int p = bx * 128 + wc * 64 + ni * 16 + lm;
      size_t off = ((size_t)(bb * NPIX + p)) * 512 + mt * 128 + bm;
      f32x4 v = acc[mi][ni];
      storeq4(&YT[off], v[0] + b0, v[1] + b1, v[2] + b2, v[3] + b3);
    }
  }
}

/* =====================================================================
 * Kernel 3: 4-corner nearest sample + sin/cos modulation (int16 YT).
 * Validated bit-exact index path — unchanged.
 * ===================================================================== */
__global__ __launch_bounds__(128) void lte_sample(
    const short* __restrict__ YT, const float* __restrict__ coord,
    const float* __restrict__ cell, const float* __restrict__ phase_w,
    float* __restrict__ out) {
  __shared__ float lout[256 * 17];
  const int j     = threadIdx.x;          /* 0..127 */
  const int q0    = blockIdx.x * 16;      /* global over B*Q */
  const int b     = q0 >> 14;
  const int q0loc = q0 & (NPIX - 1);
  const float pw0 = phase_w[2 * j], pw1 = phase_w[2 * j + 1];
  const short* Yb = YT + ((size_t)b * NPIX) * 512;

  for (int qi = 0; qi < 16; ++qi) {
    const int qg = q0 + qi;
    const float c0  = coord[2 * qg], c1 = coord[2 * qg + 1];
    const float ce0 = cell[2 * qg],  ce1 = cell[2 * qg + 1];
    const float ph  = (ce0 * 128.0f) * pw0 + (ce1 * 128.0f) * pw1;
    float accC = 0.f, accS = 0.f, tot = 0.f, a3 = 0.f;
#pragma unroll
    for (int ci = 0; ci < 4; ++ci) {     /* (vx,vy): (-,-),(-,+),(+,-),(+,+) */
      const float s0 = (ci & 2) ? SHP : SHM;
      const float s1 = (ci & 1) ? SHP : SHM;
      float cx = fminf(fmaxf(c0 + s0, CLO), CHI);
      float cy = fminf(fmaxf(c1 + s1, CLO), CHI);
      float ty = ((cx + 1.0f) * 128.0f - 1.0f) * 0.5f;
      float tx = ((cy + 1.0f) * 128.0f - 1.0f) * 0.5f;
      float fy = fminf(fmaxf(rintf(ty), 0.f), 127.f);   /* round half-even */
      float fx = fminf(fmaxf(rintf(tx), 0.f), 127.f);
      int iy = (int)fy, ix = (int)fx;
      float qcy = -1.0f + (2.0f * fy + 1.0f) * (1.0f / 128.0f);
      float qcx = -1.0f + (2.0f * fx + 1.0f) * (1.0f / 128.0f);
      float rel0 = (c0 - qcy) * 128.0f;
      float rel1 = (c1 - qcx) * 128.0f;
      float ar = fabsf(rel0 * rel1);
      tot += ar + 1e-9f;
      if (ci == 3) a3 = ar;
      const short* bp = Yb + ((size_t)(iy * 128 + ix)) * 512;
      float coefA = ldq(bp + j);          /* coef channel j    */
      float coefB = ldq(bp + 128 + j);    /* coef channel j+128 */
      float f0, f1;
      ldqpair(bp + 256 + 2 * j, f0, f1);  /* freq pair (2j,2j+1) */
      float f = f0 * rel0 + f1 * rel1 + ph;
      float ang = PIF * f;
      accC += coefA * __cosf(ang);
      accS += coefB * __sinf(ang);
    }
    const float wgt = a3 / tot;
    lout[j * 17 + qi]         = accC * wgt;
    lout[(j + 128) * 17 + qi] = accS * wgt;
  }
  __syncthreads();
#pragma unroll
  for (int pass = 0; pass < 8; ++pass) {
    int c  = pass * 32 + (j >> 2);
    int qf = (j & 3) * 4;
    float4 v;
    v.x = lout[c * 17 + qf];     v.y = lout[c * 17 + qf + 1];
    v.z = lout[c * 17 + qf + 2]; v.w = lout[c * 17 + qf + 3];
    *(float4*)(out + (((size_t)(b * 256 + c)) << 14) + q0loc + qf) = v;
  }
}

extern "C" void kernel_launch(void* const* d_in, const int* in_sizes, int n_in,
                              void* d_out, int out_size, void* d_ws, size_t ws_size,
                              hipStream_t stream) {
  const float* inp     = (const float*)d_in[0];
  const float* coord   = (const float*)d_in[1];
  const float* cell    = (const float*)d_in[2];
  const float* coef_w  = (const float*)d_in[3];
  const float* coef_b  = (const float*)d_in[4];
  const float* freq_w  = (const float*)d_in[5];
  const float* freq_b  = (const float*)d_in[6];
  const float* phase_w = (const float*)d_in[7];
  float* out = (float*)d_out;

  /* ws: Awp fp16 (0.59MB) | xp_pad fp16 (8.65MB + slack) | YT int16 (67MB) */
  f16* Awp = (f16*)d_ws;
  f16* xp  = (f16*)((char*)d_ws + (size_t)WELEM * 2);
  short* YT = (short*)((char*)d_ws + (size_t)WELEM * 2
                       + ((size_t)NB * XROWS + 8) * 64 * 2);

  lte_prep_w<<<dim3(1152), dim3(256), 0, stream>>>(coef_w, freq_w, Awp);
  lte_prep_x<<<dim3((NB * XROWS + 255) / 256), dim3(256), 0, stream>>>(inp, xp);
  lte_conv_gemm<<<dim3(128, 4, 4), dim3(256), 0, stream>>>(xp, Awp, coef_b, freq_b, YT);
  lte_sample<<<dim3(4096), dim3(128), 0, stream>>>(YT, coord, cell, phase_w, out);
}